// Round 9
// baseline (217.336 us; speedup 1.0000x reference)
//
#include <hip/hip_runtime.h>
#include <hip/hip_bf16.h>
#include <math.h>

#define N 20000
#define E 160000
#define MUL 64
#define EDIM 8
#define NZ 4

#define INV_SQRT_MUL 0.125f
#define INV_E 0.35355339059327373f
#define INV_N 0.35355339059327373f
#define INV2 0.08838834764831845f
#define INV_SC 0.0625f
#define INV_SQRT3 0.5773502691896258f

typedef unsigned short u16;
typedef unsigned int u32;
typedef short bf16x8 __attribute__((ext_vector_type(8)));
typedef float f32x4 __attribute__((ext_vector_type(4)));

__device__ __forceinline__ float silu(float v) {
    return v / (1.0f + __expf(-v));
}
__device__ __forceinline__ u16 f2bf(float f) {
    union { float f; unsigned int u; } v; v.f = f;
    unsigned int r = (v.u + 0x7FFFu + ((v.u >> 16) & 1u)) >> 16;
    return (u16)r;
}
__device__ __forceinline__ float bflo(u32 p) {
    union { unsigned int u; float f; } v; v.u = p << 16; return v.f;
}
__device__ __forceinline__ float bfhi(u32 p) {
    union { unsigned int u; float f; } v; v.u = p & 0xFFFF0000u; return v.f;
}
#define MFMA(a, b, c) __builtin_amdgcn_mfma_f32_16x16x32_bf16(a, b, c, 0, 0, 0)

// Layouts:
//  x1p [3N][64] bf16(x1)
//  hc  [N][64][4] bf16 AoS = g0,g1x,g1y,g1z (lin1 output, built in k_front)
//  Bt1m [128][128]=W20^T; Bt1z [4][128][64]=Wsc0_z^T*INV_SC
//  Bt2 [64][384] (k<128: W21^T; k>=128: Wsc1 flat u*4+z)
//  head[n]: last edge with dst=n (-1 none); nl[e] = {prev edge, src}
//  (A1/A2g global buffers DELETED: gather output now lives only in k_gf LDS)

// ---------------------------------------------------------------------------
// Front v3: grid-partitioned [prep+lin1MFMA | wconv | hid | list-build]
// ---------------------------------------------------------------------------
#define PREP_B  1250
#define WCONV_B 288
#define HID_B   5000
#define LIST_B  625

__global__ __launch_bounds__(256) void k_front(
    const float* __restrict__ x,
    const float* __restrict__ eemb, const int* __restrict__ eidx,
    const float* __restrict__ W20, const float* __restrict__ Wsc0,
    const float* __restrict__ W21, const float* __restrict__ Wsc1,
    const float* __restrict__ W0, const float* __restrict__ W1,
    const float* __restrict__ Wm1,
    u16* __restrict__ x1p,
    u16* __restrict__ Bt1m, u16* __restrict__ Bt1z, u16* __restrict__ Bt2,
    u16* __restrict__ hc, float* __restrict__ hid,
    int* __restrict__ head, int2* __restrict__ nl)
{
    const int b = blockIdx.x;
    const int tid = threadIdx.x;

    if (b < PREP_B) {
        __shared__ float xr[16][256];          // 16 KB
        __shared__ u16 sxb0[16 * 68];          // bf16 x0 tile, +4 pad
        __shared__ u16 sxb1[48 * 68];          // bf16 x1 tile, +4 pad
        const int n0 = b * 16;
        const int lane = tid & 63, wave = tid >> 6;
        const int quad = lane >> 4, l16 = lane & 15;

        // B-fragments from raw W0/W1 (16KB, L1-hot across blocks), pre-sync.
        const float* Wsrc = (wave == 0) ? W0 : W1;
        bf16x8 bw[4][2];
        #pragma unroll
        for (int ct = 0; ct < 4; ++ct)
            #pragma unroll
            for (int kk = 0; kk < 2; ++kk)
                #pragma unroll
                for (int j = 0; j < 8; ++j)
                    bw[ct][kk][j] = (short)f2bf(
                        Wsrc[(kk * 32 + quad * 8 + j) * 64 + ct * 16 + l16]
                        * INV_SQRT_MUL);

        #pragma unroll
        for (int t = 0; t < 16; ++t)
            xr[t][tid] = x[(size_t)(n0 + t) * 256 + tid];
        __syncthreads();

        // convert: x0 -> sxb0; x1 (deinterleave) -> sxb1 + x1p
        #pragma unroll
        for (int i = 0; i < 4; ++i) {
            const int idx = tid * 4 + i;          // 0..1023
            const int row = idx >> 6, col = idx & 63;
            sxb0[row * 68 + col] = f2bf(xr[row][col]);
        }
        #pragma unroll
        for (int i = 0; i < 12; ++i) {
            const int idx = tid * 12 + i;         // 0..3071
            const int lrow = idx >> 6, u = idx & 63;
            const int t = (lrow * 21846) >> 16;   // lrow/3
            const int d = lrow - t * 3;
            const u16 v = f2bf(xr[t][64 + u * 3 + d]);
            sxb1[lrow * 68 + u] = v;
            x1p[((size_t)(3 * n0) + lrow) * 64 + u] = v;
        }
        __syncthreads();

        // lin1 MFMA -> hc
        f32x4 acc[4] = {};
        if (wave == 0) {
            #pragma unroll
            for (int kk = 0; kk < 2; ++kk) {
                bf16x8 a = *(const bf16x8*)(sxb0 + l16 * 68 + kk * 32 + quad * 8);
                #pragma unroll
                for (int ct = 0; ct < 4; ++ct)
                    acc[ct] = MFMA(a, bw[ct][kk], acc[ct]);
            }
            #pragma unroll
            for (int ct = 0; ct < 4; ++ct)
                #pragma unroll
                for (int r = 0; r < 4; ++r) {
                    const int row = n0 + quad * 4 + r;
                    const int vv = ct * 16 + l16;
                    hc[(size_t)row * 256 + vv * 4] = f2bf(acc[ct][r]);
                }
        } else {
            const int rt = wave - 1;              // 0..2
            #pragma unroll
            for (int kk = 0; kk < 2; ++kk) {
                bf16x8 a = *(const bf16x8*)(sxb1 + (rt * 16 + l16) * 68 + kk * 32 + quad * 8);
                #pragma unroll
                for (int ct = 0; ct < 4; ++ct)
                    acc[ct] = MFMA(a, bw[ct][kk], acc[ct]);
            }
            #pragma unroll
            for (int ct = 0; ct < 4; ++ct)
                #pragma unroll
                for (int r = 0; r < 4; ++r) {
                    const int lrow = rt * 16 + quad * 4 + r;   // 0..47
                    const int t = (lrow * 21846) >> 16;        // lrow/3
                    const int d = lrow - t * 3;
                    const int vv = ct * 16 + l16;
                    hc[(size_t)(n0 + t) * 256 + vv * 4 + 1 + d] = f2bf(acc[ct][r]);
                }
        }
    } else if (b < PREP_B + WCONV_B) {
        const int i = (b - PREP_B) * 256 + tid;   // 0..73727
        if (i < 16384) {
            int w = i >> 7, k = i & 127;
            Bt1m[i] = f2bf(W20[k * 128 + w]);
        } else if (i < 49152) {
            int j = i - 16384;
            int z = j >> 13, r = j & 8191, w = r >> 6, k = r & 63;
            Bt1z[j] = f2bf(Wsc0[(k * 4 + z) * 128 + w] * INV_SC);
        } else {
            int j = i - 49152;
            int w = j / 384, k = j % 384;
            float v = (k < 128) ? W21[k * 64 + w] : Wsc1[(k - 128) * 64 + w];
            Bt2[j] = f2bf(v);
        }
    } else if (b < PREP_B + WCONV_B + HID_B) {
        const int i = (b - PREP_B - WCONV_B) * 256 + tid;
        const int e = i >> 3, k = i & 7;
        float s = 0.f;
        #pragma unroll
        for (int j = 0; j < 8; ++j)
            s += eemb[(size_t)e * 8 + j] * Wm1[j * 8 + k];
        hid[i] = silu(s * INV_E);
    } else {
        const int e = (b - PREP_B - WCONV_B - HID_B) * 256 + tid;
        if (e < E) {
            int src = eidx[e];
            int dst = eidx[E + e];
            int old = atomicExch(&head[dst], e);
            nl[e] = make_int2(old, src);
        }
    }
}

// ---------------------------------------------------------------------------
// k_gf: merged gather + post-GEMM + epilogue.
//   Phase A (chase): 8 waves x 2 nodes, dual interleaved linked-list chains
//   (v7 math), results written bf16 DIRECTLY into swizzled LDS tiles
//   (ds_write, so swizzle is exact — no global_load_lds constraint).
//   Phase B: fused GEMM from LDS (sA1/sA2) + B-matrices (L2-hot, loaded
//   post-barrier to keep chase-phase VGPR <= 128); x0-bf16 fragments rebuilt
//   on the fly from x (identical f2bf rounding as the deleted A1 tail).
//   Deletes: A1/A2g global round-trip (~23MB), fused staging, one launch.
// ---------------------------------------------------------------------------
__global__ __launch_bounds__(512, 4) void k_gf(
    const int* __restrict__ head, const int2* __restrict__ nl,
    const float* __restrict__ eattr, const float* __restrict__ hid,
    const u32* __restrict__ hc2, const float* __restrict__ Wm2,
    const u16* __restrict__ x1p,
    const u16* __restrict__ Bt1m, const u16* __restrict__ Bt1z,
    const u16* __restrict__ Bt2,
    const float* __restrict__ attrs, const float* __restrict__ x,
    float* __restrict__ out)
{
    const int lane = threadIdx.x & 63;
    const int wave = threadIdx.x >> 6;      // 0..7
    const int quad = lane >> 4, l16 = lane & 15;
    const int n0 = blockIdx.x * 16;
    const float4* at4 = (const float4*)attrs;

    __shared__ u16 sA1[16 * 128];           //  4 KB: gathered s0 (swizzled)
    __shared__ u16 sA2[48 * 128];           // 12 KB: gathered s1 (swizzled)
    __shared__ float st0[16][132];
    __shared__ float st1[48][68];

    // ---- Phase A: dual-chain chase for nodes n0+2w, n0+2w+1 ----
    float wm0[8], wm1[8], wm2r[8], wm3[8];
    #pragma unroll
    for (int k = 0; k < 8; ++k) {
        wm0[k]  = Wm2[k * 256 + lane];
        wm1[k]  = Wm2[k * 256 + 64 + lane];
        wm2r[k] = Wm2[k * 256 + 128 + lane];
        wm3[k]  = Wm2[k * 256 + 192 + lane];
    }

    auto edgeC = [&](const float4& ea, const float4& hA, const float4& hB,
                     const uint2& hp, float& a0, float& a3,
                     float* s1a, float* s1b) {
        float w1 = hA.x*wm0[0]+hA.y*wm0[1]+hA.z*wm0[2]+hA.w*wm0[3]
                 + hB.x*wm0[4]+hB.y*wm0[5]+hB.z*wm0[6]+hB.w*wm0[7];
        float w2 = hA.x*wm1[0]+hA.y*wm1[1]+hA.z*wm1[2]+hA.w*wm1[3]
                 + hB.x*wm1[4]+hB.y*wm1[5]+hB.z*wm1[6]+hB.w*wm1[7];
        float w3 = hA.x*wm2r[0]+hA.y*wm2r[1]+hA.z*wm2r[2]+hA.w*wm2r[3]
                 + hB.x*wm2r[4]+hB.y*wm2r[5]+hB.z*wm2r[6]+hB.w*wm2r[7];
        float w4 = hA.x*wm3[0]+hA.y*wm3[1]+hA.z*wm3[2]+hA.w*wm3[3]
                 + hB.x*wm3[4]+hB.y*wm3[5]+hB.z*wm3[6]+hB.w*wm3[7];
        const float g0 = bflo(hp.x), g1x = bfhi(hp.x);
        const float g1y = bflo(hp.y), g1z = bfhi(hp.y);
        a0 += w1 * g0 * ea.x;
        a3 += w4 * (g1x * ea.y + g1y * ea.z + g1z * ea.w);
        const float wg = w2 * g0, w3a = w3 * ea.x;
        s1a[0] += wg * ea.y;  s1a[1] += wg * ea.z;  s1a[2] += wg * ea.w;
        s1b[0] += w3a * g1x;  s1b[1] += w3a * g1y;  s1b[2] += w3a * g1z;
    };

    const int nA = n0 + 2 * wave;
    float aA0 = 0.f, aA3 = 0.f, sAa[3] = {0,0,0}, sAb[3] = {0,0,0};
    float aB0 = 0.f, aB3 = 0.f, sBa[3] = {0,0,0}, sBb[3] = {0,0,0};

    int eA = head[nA];
    int eB = head[nA + 1];
    int2 vA = make_int2(-1, 0), vB = make_int2(-1, 0);
    float4 eaA, hAA, hBA; uint2 hpA;
    float4 eaB, hAB, hBB; uint2 hpB;
    if (eA != -1) {
        vA  = nl[eA];
        eaA = ((const float4*)eattr)[eA];
        hAA = ((const float4*)hid)[(size_t)eA * 2];
        hBA = ((const float4*)hid)[(size_t)eA * 2 + 1];
        hpA = ((const uint2*)hc2)[(size_t)vA.y * 64 + lane];
    }
    if (eB != -1) {
        vB  = nl[eB];
        eaB = ((const float4*)eattr)[eB];
        hAB = ((const float4*)hid)[(size_t)eB * 2];
        hBB = ((const float4*)hid)[(size_t)eB * 2 + 1];
        hpB = ((const uint2*)hc2)[(size_t)vB.y * 64 + lane];
    }

    while (eA != -1 || eB != -1) {
        int enA = -1, enB = -1;
        int2 vnA = make_int2(-1, 0), vnB = make_int2(-1, 0);
        float4 eaNA, hANA, hBNA; uint2 hpNA;
        float4 eaNB, hANB, hBNB; uint2 hpNB;
        if (eA != -1) {
            enA = vA.x;
            if (enA != -1) {
                vnA  = nl[enA];
                eaNA = ((const float4*)eattr)[enA];
                hANA = ((const float4*)hid)[(size_t)enA * 2];
                hBNA = ((const float4*)hid)[(size_t)enA * 2 + 1];
                hpNA = ((const uint2*)hc2)[(size_t)vnA.y * 64 + lane];
            }
        }
        if (eB != -1) {
            enB = vB.x;
            if (enB != -1) {
                vnB  = nl[enB];
                eaNB = ((const float4*)eattr)[enB];
                hANB = ((const float4*)hid)[(size_t)enB * 2];
                hBNB = ((const float4*)hid)[(size_t)enB * 2 + 1];
                hpNB = ((const uint2*)hc2)[(size_t)vnB.y * 64 + lane];
            }
        }

        if (eA != -1) edgeC(eaA, hAA, hBA, hpA, aA0, aA3, sAa, sAb);
        if (eB != -1) edgeC(eaB, hAB, hBB, hpB, aB0, aB3, sBa, sBb);

        if (eA != -1) { eA = enA; vA = vnA; eaA = eaNA; hAA = hANA; hBA = hBNA; hpA = hpNA; }
        if (eB != -1) { eB = enB; vB = vnB; eaB = eaNB; hAB = hANB; hBB = hBNB; hpB = hpNB; }
    }

    // write results bf16 into swizzled LDS: elem(row,col) at row*128+(col^((row&7)<<3))
    {
        const float f = INV_E * INV_N * INV2;
        const int rrA = 2 * wave, rrB = 2 * wave + 1;
        sA1[rrA * 128 + (lane ^ ((rrA & 7) << 3))]        = f2bf(aA0 * f);
        sA1[rrA * 128 + ((64 + lane) ^ ((rrA & 7) << 3))] = f2bf(aA3 * f * INV_SQRT3);
        sA1[rrB * 128 + (lane ^ ((rrB & 7) << 3))]        = f2bf(aB0 * f);
        sA1[rrB * 128 + ((64 + lane) ^ ((rrB & 7) << 3))] = f2bf(aB3 * f * INV_SQRT3);
        #pragma unroll
        for (int d = 0; d < 3; ++d) {
            const int lrA = rrA * 3 + d, lrB = rrB * 3 + d;
            sA2[lrA * 128 + (lane ^ ((lrA & 7) << 3))]        = f2bf(sAa[d] * f);
            sA2[lrA * 128 + ((64 + lane) ^ ((lrA & 7) << 3))] = f2bf(sAb[d] * f);
            sA2[lrB * 128 + (lane ^ ((lrB & 7) << 3))]        = f2bf(sBa[d] * f);
            sA2[lrB * 128 + ((64 + lane) ^ ((lrB & 7) << 3))] = f2bf(sBb[d] * f);
        }
    }
    __syncthreads();

    // ---- Phase B: fused GEMM from LDS ----
    // epilogue x rows issued first (HBM/L3, consumed last)
    const int c = threadIdx.x & 255;
    const int th = threadIdx.x >> 8;        // 0,1
    float xv[8];
    #pragma unroll
    for (int i = 0; i < 8; ++i)
        xv[i] = x[(size_t)(n0 + i * 2 + th) * 256 + c];

    if (wave < 4) {
        // ---- t0 path ----
        const u16* b0p  = Bt1m + (size_t)(wave * 16 + l16) * 128 + quad * 8;
        const u16* b1p  = Bt1m + (size_t)((wave + 4) * 16 + l16) * 128 + quad * 8;
        const u16* bz0p = Bt1z + (size_t)(wave * 16 + l16) * 64 + quad * 8;
        const u16* bz1p = Bt1z + (size_t)((wave + 4) * 16 + l16) * 64 + quad * 8;

        // x0 bf16 fragments rebuilt from x (same f2bf as deleted A1 tail)
        bf16x8 a0s[2];
        #pragma unroll
        for (int kt = 0; kt < 2; ++kt) {
            const float* xp = x + (size_t)(n0 + l16) * 256 + kt * 32 + quad * 8;
            const float4 xa = *(const float4*)xp;
            const float4 xb = *(const float4*)(xp + 4);
            a0s[kt][0] = (short)f2bf(xa.x); a0s[kt][1] = (short)f2bf(xa.y);
            a0s[kt][2] = (short)f2bf(xa.z); a0s[kt][3] = (short)f2bf(xa.w);
            a0s[kt][4] = (short)f2bf(xb.x); a0s[kt][5] = (short)f2bf(xb.y);
            a0s[kt][6] = (short)f2bf(xb.z); a0s[kt][7] = (short)f2bf(xb.w);
        }

        f32x4 m0 = {}, m1 = {};
        #pragma unroll
        for (int kt = 0; kt < 4; ++kt) {
            const int off = l16 * 128 + kt * 32 + quad * 8;
            bf16x8 a0 = *(const bf16x8*)(sA1 + (off ^ ((l16 & 7) << 3)));
            bf16x8 b0 = *(const bf16x8*)(b0p + kt * 32);
            bf16x8 b1 = *(const bf16x8*)(b1p + kt * 32);
            m0 = MFMA(a0, b0, m0);
            m1 = MFMA(a0, b1, m1);
        }
        f32x4 z0[4] = {}, z1[4] = {};
        #pragma unroll
        for (int z = 0; z < 4; ++z)
            #pragma unroll
            for (int kt = 0; kt < 2; ++kt) {
                bf16x8 c0 = *(const bf16x8*)(bz0p + z * 8192 + kt * 32);
                bf16x8 c1 = *(const bf16x8*)(bz1p + z * 8192 + kt * 32);
                z0[z] = MFMA(a0s[kt], c0, z0[z]);
                z1[z] = MFMA(a0s[kt], c1, z1[z]);
            }

        #pragma unroll
        for (int r = 0; r < 4; ++r) {
            const int r0 = quad * 4 + r;
            const float4 a = at4[n0 + r0];
            st0[r0][wave * 16 + l16] =
                m0[r] + a.x * z0[0][r] + a.y * z0[1][r] + a.z * z0[2][r] + a.w * z0[3][r];
            st0[r0][(wave + 4) * 16 + l16] =
                m1[r] + a.x * z1[0][r] + a.y * z1[1][r] + a.z * z1[2][r] + a.w * z1[3][r];
        }
    } else {
        // ---- t1 path ----
        const int ct = wave - 4;
        const u16* b2p = Bt2 + (size_t)(ct * 16 + l16) * 384 + quad * 8;
        const u16* xq0 = x1p + (size_t)(3 * n0 + l16) * 64 + quad * 2;

        u32 XQ[3][8];
        #pragma unroll
        for (int rt = 0; rt < 3; ++rt)
            #pragma unroll
            for (int kt = 0; kt < 8; ++kt)
                XQ[rt][kt] = *(const u32*)(xq0 + rt * 16 * 64 + kt * 8);
        float4 atv[3];
        #pragma unroll
        for (int rt = 0; rt < 3; ++rt) {
            const int ro = rt * 16 + l16;            // 0..47
            const int nn = (ro * 21846) >> 16;       // ro/3
            const float4 v = at4[n0 + nn];
            atv[rt].x = v.x * INV_SC; atv[rt].y = v.y * INV_SC;
            atv[rt].z = v.z * INV_SC; atv[rt].w = v.w * INV_SC;
        }

        f32x4 mt[3] = {};
        #pragma unroll
        for (int kt = 0; kt < 4; ++kt) {
            bf16x8 b2 = *(const bf16x8*)(b2p + kt * 32);
            #pragma unroll
            for (int rt = 0; rt < 3; ++rt) {
                const int row = rt * 16 + l16;
                const int off = row * 128 + kt * 32 + quad * 8;
                bf16x8 a = *(const bf16x8*)(sA2 + (off ^ ((row & 7) << 3)));
                mt[rt] = MFMA(a, b2, mt[rt]);
            }
        }
        #pragma unroll
        for (int kt = 0; kt < 8; ++kt) {
            bf16x8 b2 = *(const bf16x8*)(b2p + 128 + kt * 32);
            #pragma unroll
            for (int rt = 0; rt < 3; ++rt) {
                const u32 xp = XQ[rt][kt];
                const float xa = bflo(xp), xb = bfhi(xp);
                bf16x8 af;
                af[0] = (short)f2bf(xa * atv[rt].x); af[1] = (short)f2bf(xa * atv[rt].y);
                af[2] = (short)f2bf(xa * atv[rt].z); af[3] = (short)f2bf(xa * atv[rt].w);
                af[4] = (short)f2bf(xb * atv[rt].x); af[5] = (short)f2bf(xb * atv[rt].y);
                af[6] = (short)f2bf(xb * atv[rt].z); af[7] = (short)f2bf(xb * atv[rt].w);
                mt[rt] = MFMA(af, b2, mt[rt]);
            }
        }

        #pragma unroll
        for (int r = 0; r < 4; ++r) {
            const int r0 = quad * 4 + r;
            st1[r0][ct * 16 + l16]      = mt[0][r];
            st1[16 + r0][ct * 16 + l16] = mt[1][r];
            st1[32 + r0][ct * 16 + l16] = mt[2][r];
        }
    }

    __syncthreads();

    #pragma unroll
    for (int i = 0; i < 8; ++i) {
        const int t = i * 2 + th;
        float o;
        if (c < 64) {
            o = xv[i] + silu(st0[t][c]);
        } else {
            int r = c - 64;
            int w = (r * 21846) >> 16;      // r/3
            int d = r - w * 3;
            o = xv[i] + silu(st0[t][64 + w]) * st1[t * 3 + d][w];
        }
        out[(size_t)(n0 + t) * 256 + c] = o;
    }
}

extern "C" void kernel_launch(void* const* d_in, const int* in_sizes, int n_in,
                              void* d_out, int out_size, void* d_ws, size_t ws_size,
                              hipStream_t stream) {
    const float* node_feats = (const float*)d_in[0];
    const float* node_attrs = (const float*)d_in[1];
    const float* edge_attrs = (const float*)d_in[2];
    const float* edge_emb   = (const float*)d_in[3];
    const float* W_lin1_0   = (const float*)d_in[4];
    const float* W_lin1_1   = (const float*)d_in[5];
    const float* W_mlp1     = (const float*)d_in[6];
    const float* W_mlp2     = (const float*)d_in[7];
    const float* W_lin2_0   = (const float*)d_in[8];
    const float* W_lin2_1   = (const float*)d_in[9];
    const float* W_sc0      = (const float*)d_in[10];
    const float* W_sc1      = (const float*)d_in[11];
    const int*   edge_index = (const int*)d_in[12];
    float* out = (float*)d_out;

    char* p = (char*)d_ws;
    float* hid = (float*)p;                 p += (size_t)E * 8 * 4;
    u16* hc    = (u16*)p;                   p += (size_t)N * 256 * 2;
    u16* x1p   = (u16*)p;                   p += (size_t)N * 3 * 64 * 2;
    u16* Bt1m  = (u16*)p;                   p += 16384 * 2;
    u16* Bt1z  = (u16*)p;                   p += 32768 * 2;
    u16* Bt2   = (u16*)p;                   p += 24576 * 2;
    int* head  = (int*)p;                   p += N * 4;
    int2* nl   = (int2*)p;                  p += (size_t)E * 8;

    hipMemsetAsync(head, 0xFF, N * sizeof(int), stream);

    k_front<<<PREP_B + WCONV_B + HID_B + LIST_B, 256, 0, stream>>>(
        node_feats, edge_emb, edge_index,
        W_lin2_0, W_sc0, W_lin2_1, W_sc1, W_lin1_0, W_lin1_1, W_mlp1,
        x1p, Bt1m, Bt1z, Bt2, hc, hid, head, nl);
    k_gf<<<1250, 512, 0, stream>>>(head, nl, edge_attrs, hid,
                                   (const u32*)hc, W_mlp2, x1p,
                                   Bt1m, Bt1z, Bt2,
                                   node_attrs, node_feats, out);
}

// Round 10
// 192.865 us; speedup vs baseline: 1.1269x; 1.1269x over previous
//
#include <hip/hip_runtime.h>
#include <hip/hip_bf16.h>
#include <math.h>

#define N 20000
#define E 160000
#define MUL 64
#define EDIM 8
#define NZ 4

#define INV_SQRT_MUL 0.125f
#define INV_E 0.35355339059327373f
#define INV_N 0.35355339059327373f
#define INV2 0.08838834764831845f
#define INV_SC 0.0625f
#define INV_SQRT3 0.5773502691896258f

typedef unsigned short u16;
typedef unsigned int u32;
typedef short bf16x8 __attribute__((ext_vector_type(8)));
typedef float f32x4 __attribute__((ext_vector_type(4)));

__device__ __forceinline__ float silu(float v) {
    return v / (1.0f + __expf(-v));
}
__device__ __forceinline__ u16 f2bf(float f) {
    union { float f; unsigned int u; } v; v.f = f;
    unsigned int r = (v.u + 0x7FFFu + ((v.u >> 16) & 1u)) >> 16;
    return (u16)r;
}
__device__ __forceinline__ float bflo(u32 p) {
    union { unsigned int u; float f; } v; v.u = p << 16; return v.f;
}
__device__ __forceinline__ float bfhi(u32 p) {
    union { unsigned int u; float f; } v; v.u = p & 0xFFFF0000u; return v.f;
}
#define MFMA(a, b, c) __builtin_amdgcn_mfma_f32_16x16x32_bf16(a, b, c, 0, 0, 0)

// async global->LDS: per-lane global src, wave-uniform LDS base (+lane*16 by HW)
__device__ __forceinline__ void gll16(const u16* g, u16* l) {
    __builtin_amdgcn_global_load_lds(
        (const __attribute__((address_space(1))) u32*)g,
        (__attribute__((address_space(3))) u32*)l, 16, 0, 0);
}

// Layouts:
//  A1  [N][192]:  0..127 gathered s0 (scales folded), 128..191 bf16(x0)
//  A2g [3N][128]: gathered s1 only
//  x1p [3N][64] bf16(x1)
//  hc  [N][64][4] bf16 AoS = g0,g1x,g1y,g1z (lin1 output, built in k_front)
//  Bt1m [128][128]=W20^T; Bt1z [4][128][64]=Wsc0_z^T*INV_SC
//  Bt2 [64][384] (k<128: W21^T; k>=128: Wsc1 flat u*4+z)
//  head[n]: last edge with dst=n (-1 none); nl[e] = {prev edge, src}

// ---------------------------------------------------------------------------
// Front v4: grid-partitioned [prep+lin1MFMA | wconv | hid | list-build]
//   hid partition rewritten 1-thread-per-edge (was 8 threads/edge with 128
//   redundant global loads each): Wm1 staged in LDS once/block, eemb read
//   2xfloat4, 8 outputs stored 2xfloat4. HID_B 5000 -> 625.
// ---------------------------------------------------------------------------
#define PREP_B  1250
#define WCONV_B 288
#define HID_B   625
#define LIST_B  625

__global__ __launch_bounds__(256) void k_front(
    const float* __restrict__ x,
    const float* __restrict__ eemb, const int* __restrict__ eidx,
    const float* __restrict__ W20, const float* __restrict__ Wsc0,
    const float* __restrict__ W21, const float* __restrict__ Wsc1,
    const float* __restrict__ W0, const float* __restrict__ W1,
    const float* __restrict__ Wm1,
    u16* __restrict__ A1, u16* __restrict__ x1p,
    u16* __restrict__ Bt1m, u16* __restrict__ Bt1z, u16* __restrict__ Bt2,
    u16* __restrict__ hc, float* __restrict__ hid,
    int* __restrict__ head, int2* __restrict__ nl)
{
    const int b = blockIdx.x;
    const int tid = threadIdx.x;

    if (b < PREP_B) {
        __shared__ float xr[16][256];          // 16 KB
        __shared__ u16 sxb0[16 * 68];          // bf16 x0 tile, +4 pad
        __shared__ u16 sxb1[48 * 68];          // bf16 x1 tile, +4 pad
        const int n0 = b * 16;
        const int lane = tid & 63, wave = tid >> 6;
        const int quad = lane >> 4, l16 = lane & 15;

        // B-fragments from raw W0/W1 (16KB, L1-hot across blocks), pre-sync.
        const float* Wsrc = (wave == 0) ? W0 : W1;
        bf16x8 bw[4][2];
        #pragma unroll
        for (int ct = 0; ct < 4; ++ct)
            #pragma unroll
            for (int kk = 0; kk < 2; ++kk)
                #pragma unroll
                for (int j = 0; j < 8; ++j)
                    bw[ct][kk][j] = (short)f2bf(
                        Wsrc[(kk * 32 + quad * 8 + j) * 64 + ct * 16 + l16]
                        * INV_SQRT_MUL);

        #pragma unroll
        for (int t = 0; t < 16; ++t)
            xr[t][tid] = x[(size_t)(n0 + t) * 256 + tid];
        __syncthreads();

        // convert: x0 -> sxb0 + A1 tail; x1 (deinterleave) -> sxb1 + x1p
        #pragma unroll
        for (int i = 0; i < 4; ++i) {
            const int idx = tid * 4 + i;          // 0..1023
            const int row = idx >> 6, col = idx & 63;
            const u16 v = f2bf(xr[row][col]);
            sxb0[row * 68 + col] = v;
            A1[(size_t)(n0 + row) * 192 + 128 + col] = v;
        }
        #pragma unroll
        for (int i = 0; i < 12; ++i) {
            const int idx = tid * 12 + i;         // 0..3071
            const int lrow = idx >> 6, u = idx & 63;
            const int t = (lrow * 21846) >> 16;   // lrow/3
            const int d = lrow - t * 3;
            const u16 v = f2bf(xr[t][64 + u * 3 + d]);
            sxb1[lrow * 68 + u] = v;
            x1p[((size_t)(3 * n0) + lrow) * 64 + u] = v;
        }
        __syncthreads();

        // lin1 MFMA -> hc
        f32x4 acc[4] = {};
        if (wave == 0) {
            #pragma unroll
            for (int kk = 0; kk < 2; ++kk) {
                bf16x8 a = *(const bf16x8*)(sxb0 + l16 * 68 + kk * 32 + quad * 8);
                #pragma unroll
                for (int ct = 0; ct < 4; ++ct)
                    acc[ct] = MFMA(a, bw[ct][kk], acc[ct]);
            }
            #pragma unroll
            for (int ct = 0; ct < 4; ++ct)
                #pragma unroll
                for (int r = 0; r < 4; ++r) {
                    const int row = n0 + quad * 4 + r;
                    const int vv = ct * 16 + l16;
                    hc[(size_t)row * 256 + vv * 4] = f2bf(acc[ct][r]);
                }
        } else {
            const int rt = wave - 1;              // 0..2
            #pragma unroll
            for (int kk = 0; kk < 2; ++kk) {
                bf16x8 a = *(const bf16x8*)(sxb1 + (rt * 16 + l16) * 68 + kk * 32 + quad * 8);
                #pragma unroll
                for (int ct = 0; ct < 4; ++ct)
                    acc[ct] = MFMA(a, bw[ct][kk], acc[ct]);
            }
            #pragma unroll
            for (int ct = 0; ct < 4; ++ct)
                #pragma unroll
                for (int r = 0; r < 4; ++r) {
                    const int lrow = rt * 16 + quad * 4 + r;   // 0..47
                    const int t = (lrow * 21846) >> 16;        // lrow/3
                    const int d = lrow - t * 3;
                    const int vv = ct * 16 + l16;
                    hc[(size_t)(n0 + t) * 256 + vv * 4 + 1 + d] = f2bf(acc[ct][r]);
                }
        }
    } else if (b < PREP_B + WCONV_B) {
        const int i = (b - PREP_B) * 256 + tid;   // 0..73727
        if (i < 16384) {
            int w = i >> 7, k = i & 127;
            Bt1m[i] = f2bf(W20[k * 128 + w]);
        } else if (i < 49152) {
            int j = i - 16384;
            int z = j >> 13, r = j & 8191, w = r >> 6, k = r & 63;
            Bt1z[j] = f2bf(Wsc0[(k * 4 + z) * 128 + w] * INV_SC);
        } else {
            int j = i - 49152;
            int w = j / 384, k = j % 384;
            float v = (k < 128) ? W21[k * 64 + w] : Wsc1[(k - 128) * 64 + w];
            Bt2[j] = f2bf(v);
        }
    } else if (b < PREP_B + WCONV_B + HID_B) {
        // hid v2: one thread per edge; Wm1 in LDS; vectorized eemb/hid.
        __shared__ float sWm1[64];
        if (tid < 64) sWm1[tid] = Wm1[tid];
        __syncthreads();
        const int e = (b - PREP_B - WCONV_B) * 256 + tid;   // < E exactly
        const float4 ea = ((const float4*)eemb)[(size_t)e * 2];
        const float4 eb = ((const float4*)eemb)[(size_t)e * 2 + 1];
        float r[8];
        #pragma unroll
        for (int k = 0; k < 8; ++k) {
            float s = ea.x * sWm1[0 * 8 + k] + ea.y * sWm1[1 * 8 + k]
                    + ea.z * sWm1[2 * 8 + k] + ea.w * sWm1[3 * 8 + k]
                    + eb.x * sWm1[4 * 8 + k] + eb.y * sWm1[5 * 8 + k]
                    + eb.z * sWm1[6 * 8 + k] + eb.w * sWm1[7 * 8 + k];
            r[k] = silu(s * INV_E);
        }
        float4 o0 = make_float4(r[0], r[1], r[2], r[3]);
        float4 o1 = make_float4(r[4], r[5], r[6], r[7]);
        ((float4*)hid)[(size_t)e * 2]     = o0;
        ((float4*)hid)[(size_t)e * 2 + 1] = o1;
    } else {
        const int e = (b - PREP_B - WCONV_B - HID_B) * 256 + tid;
        if (e < E) {
            int src = eidx[e];
            int dst = eidx[E + e];
            int old = atomicExch(&head[dst], e);
            nl[e] = make_int2(old, src);
        }
    }
}

// ---------------------------------------------------------------------------
// Gather v7 (best measured, 46.5us): one wave per dst node; linked-list
// chase with depth-2 pipeline. Restored byte-for-byte from round 8.
// ---------------------------------------------------------------------------
__global__ __launch_bounds__(256) void k_gather(
    const int* __restrict__ head, const int2* __restrict__ nl,
    const float* __restrict__ eattr, const float* __restrict__ hid,
    const u32* __restrict__ hc2, const float* __restrict__ Wm2,
    u16* __restrict__ A1, u16* __restrict__ A2g)
{
    const int lane = threadIdx.x & 63;
    const int n = blockIdx.x * 4 + (threadIdx.x >> 6);

    float wm0[8], wm1[8], wm2r[8], wm3[8];
    #pragma unroll
    for (int k = 0; k < 8; ++k) {
        wm0[k]  = Wm2[k * 256 + lane];
        wm1[k]  = Wm2[k * 256 + 64 + lane];
        wm2r[k] = Wm2[k * 256 + 128 + lane];
        wm3[k]  = Wm2[k * 256 + 192 + lane];
    }

    float acc0a = 0.f, acc0b = 0.f;
    float s1a[3] = {0.f, 0.f, 0.f}, s1b[3] = {0.f, 0.f, 0.f};

    int e0 = head[n];
    if (e0 != -1) {
        int2 v0 = nl[e0];
        float4 ea = ((const float4*)eattr)[e0];
        float4 hA = ((const float4*)hid)[(size_t)e0 * 2];
        float4 hB = ((const float4*)hid)[(size_t)e0 * 2 + 1];
        uint2  hp = ((const uint2*)hc2)[(size_t)v0.y * 64 + lane];
        int e1 = v0.x;
        int2 v1 = make_int2(-1, 0);
        if (e1 != -1) v1 = nl[e1];

        while (true) {
            int e2 = -1;
            int2 v2 = make_int2(-1, 0);
            float4 eaN, hAN, hBN; uint2 hpN;
            if (e1 != -1) {
                e2 = v1.x;
                if (e2 != -1) v2 = nl[e2];
                eaN = ((const float4*)eattr)[e1];
                hAN = ((const float4*)hid)[(size_t)e1 * 2];
                hBN = ((const float4*)hid)[(size_t)e1 * 2 + 1];
                hpN = ((const uint2*)hc2)[(size_t)v1.y * 64 + lane];
            }

            float w1 = hA.x*wm0[0]+hA.y*wm0[1]+hA.z*wm0[2]+hA.w*wm0[3]
                     + hB.x*wm0[4]+hB.y*wm0[5]+hB.z*wm0[6]+hB.w*wm0[7];
            float w2 = hA.x*wm1[0]+hA.y*wm1[1]+hA.z*wm1[2]+hA.w*wm1[3]
                     + hB.x*wm1[4]+hB.y*wm1[5]+hB.z*wm1[6]+hB.w*wm1[7];
            float w3 = hA.x*wm2r[0]+hA.y*wm2r[1]+hA.z*wm2r[2]+hA.w*wm2r[3]
                     + hB.x*wm2r[4]+hB.y*wm2r[5]+hB.z*wm2r[6]+hB.w*wm2r[7];
            float w4 = hA.x*wm3[0]+hA.y*wm3[1]+hA.z*wm3[2]+hA.w*wm3[3]
                     + hB.x*wm3[4]+hB.y*wm3[5]+hB.z*wm3[6]+hB.w*wm3[7];
            const float g0 = bflo(hp.x), g1x = bfhi(hp.x);
            const float g1y = bflo(hp.y), g1z = bfhi(hp.y);
            acc0a += w1 * g0 * ea.x;
            acc0b += w4 * (g1x * ea.y + g1y * ea.z + g1z * ea.w);
            const float wg = w2 * g0, w3a = w3 * ea.x;
            s1a[0] += wg * ea.y;  s1a[1] += wg * ea.z;  s1a[2] += wg * ea.w;
            s1b[0] += w3a * g1x;  s1b[1] += w3a * g1y;  s1b[2] += w3a * g1z;

            if (e1 == -1) break;
            ea = eaN; hA = hAN; hB = hBN; hp = hpN;
            e1 = e2; v1 = v2;
        }
    }

    const float f = INV_E * INV_N * INV2;
    u16* a1p = &A1[(size_t)n * 192];
    a1p[lane]      = f2bf(acc0a * f);
    a1p[64 + lane] = f2bf(acc0b * f * INV_SQRT3);
    #pragma unroll
    for (int d = 0; d < 3; ++d) {
        u16* a2p = &A2g[((size_t)n * 3 + d) * 128];
        a2p[lane]      = f2bf(s1a[d] * f);
        a2p[64 + lane] = f2bf(s1b[d] * f);
    }
}

// ---------------------------------------------------------------------------
// Fused post-GEMM + epilogue v10 (best measured, 46.0us): MLP via
// global_load_lds + preloads. Restored byte-for-byte from round 8.
// ---------------------------------------------------------------------------
__global__ __launch_bounds__(512, 4) void k_gemm_fused(
    const u16* __restrict__ A1, const u16* __restrict__ A2g,
    const u16* __restrict__ x1p,
    const u16* __restrict__ Bt1m, const u16* __restrict__ Bt1z,
    const u16* __restrict__ Bt2,
    const float* __restrict__ attrs, const float* __restrict__ x,
    float* __restrict__ out)
{
    const int lane = threadIdx.x & 63;
    const int wave = threadIdx.x >> 6;      // 0..7
    const int quad = lane >> 4, l16 = lane & 15;
    const int n0 = blockIdx.x * 16;
    const float4* at4 = (const float4*)attrs;

    __shared__ __align__(16) u16 sA1[16 * 192];   //  6144 B
    __shared__ __align__(16) u16 sA2[48 * 128];   // 12288 B
    __shared__ float st0[16][132];
    __shared__ float st1[48][68];

    // ---- stage A1/A2g tiles: 18 x 1KB async copies, swizzled source ----
    {
        const u16* gA1 = A1 + (size_t)n0 * 192;
        const u16* gA2 = A2g + (size_t)(3 * n0) * 128;
        #pragma unroll
        for (int i = 0; i < 3; ++i) {
            const int cc = wave + i * 8;
            if (cc < 6) {
                const int Lu = cc * 512 + lane * 8;
                const int row = Lu / 192;
                const int src = Lu ^ ((row & 7) << 3);
                gll16(gA1 + src, &sA1[cc * 512]);
            } else if (cc < 18) {
                const int Lu = (cc - 6) * 512 + lane * 8;
                const int row = Lu >> 7;
                const int src = Lu ^ ((row & 7) << 3);
                gll16(gA2 + src, &sA2[(cc - 6) * 512]);
            }
        }
    }

    // ---- pre-barrier register preloads (drain together at the barrier) ----
    const u16 *bz0p = nullptr, *bz1p = nullptr;
    bf16x8 PB[8], PC[8];
    u32 XQ[3][8];
    float4 atv[3];

    if (wave < 4) {
        const u16* b0p = Bt1m + (size_t)(wave * 16 + l16) * 128 + quad * 8;
        const u16* b1p = Bt1m + (size_t)((wave + 4) * 16 + l16) * 128 + quad * 8;
        bz0p = Bt1z + (size_t)(wave * 16 + l16) * 64 + quad * 8;
        bz1p = Bt1z + (size_t)((wave + 4) * 16 + l16) * 64 + quad * 8;
        #pragma unroll
        for (int kt = 0; kt < 4; ++kt) {
            PB[kt]     = *(const bf16x8*)(b0p + kt * 32);
            PB[4 + kt] = *(const bf16x8*)(b1p + kt * 32);
        }
        #pragma unroll
        for (int z = 0; z < 2; ++z)
            #pragma unroll
            for (int kt = 0; kt < 2; ++kt) {
                PC[z * 2 + kt]     = *(const bf16x8*)(bz0p + z * 8192 + kt * 32);
                PC[4 + z * 2 + kt] = *(const bf16x8*)(bz1p + z * 8192 + kt * 32);
            }
    } else {
        const int ct = wave - 4;
        const u16* b2p = Bt2 + (size_t)(ct * 16 + l16) * 384 + quad * 8;
        const u16* xq0 = x1p + (size_t)(3 * n0 + l16) * 64 + quad * 2;
        #pragma unroll
        for (int kt = 0; kt < 4; ++kt)
            PB[kt] = *(const bf16x8*)(b2p + kt * 32);
        #pragma unroll
        for (int kt = 0; kt < 8; ++kt) {
            bf16x8 v = *(const bf16x8*)(b2p + 128 + kt * 32);
            if (kt < 4) PB[4 + kt] = v; else PC[kt - 4] = v;
        }
        #pragma unroll
        for (int rt = 0; rt < 3; ++rt)
            #pragma unroll
            for (int kt = 0; kt < 8; ++kt)
                XQ[rt][kt] = *(const u32*)(xq0 + rt * 16 * 64 + kt * 8);
        #pragma unroll
        for (int rt = 0; rt < 3; ++rt) {
            const int ro = rt * 16 + l16;            // 0..47
            const int nn = (ro * 21846) >> 16;       // ro/3
            const float4 v = at4[n0 + nn];
            atv[rt].x = v.x * INV_SC; atv[rt].y = v.y * INV_SC;
            atv[rt].z = v.z * INV_SC; atv[rt].w = v.w * INV_SC;
        }
    }

    // epilogue x rows (both paths; in flight across the barrier drain)
    const int c = threadIdx.x & 255;
    const int th = threadIdx.x >> 8;        // 0,1
    float xv[8];
    #pragma unroll
    for (int i = 0; i < 8; ++i)
        xv[i] = x[(size_t)(n0 + i * 2 + th) * 256 + c];

    __syncthreads();   // one vmcnt(0) drain for staging + all preloads

    if (wave < 4) {
        // ---- t0 path ----
        f32x4 m0 = {}, m1 = {};
        #pragma unroll
        for (int kt = 0; kt < 4; ++kt) {
            const int off = l16 * 192 + kt * 32 + quad * 8;
            bf16x8 a0 = *(const bf16x8*)(sA1 + (off ^ ((l16 & 7) << 3)));
            m0 = MFMA(a0, PB[kt], m0);
            m1 = MFMA(a0, PB[4 + kt], m1);
        }
        bf16x8 a0s[2];
        #pragma unroll
        for (int kt = 0; kt < 2; ++kt) {
            const int off = l16 * 192 + 128 + kt * 32 + quad * 8;
            a0s[kt] = *(const bf16x8*)(sA1 + (off ^ ((l16 & 7) << 3)));
        }
        f32x4 z0[4] = {}, z1[4] = {};
        #pragma unroll
        for (int z = 0; z < 2; ++z)
            #pragma unroll
            for (int kt = 0; kt < 2; ++kt) {
                z0[z] = MFMA(a0s[kt], PC[z * 2 + kt], z0[z]);
                z1[z] = MFMA(a0s[kt], PC[4 + z * 2 + kt], z1[z]);
            }
        // z=2,3 B-slices loaded here (L2-hot; PC regs now free)
        #pragma unroll
        for (int z = 0; z < 2; ++z)
            #pragma unroll
            for (int kt = 0; kt < 2; ++kt) {
                bf16x8 d0 = *(const bf16x8*)(bz0p + (z + 2) * 8192 + kt * 32);
                bf16x8 d1 = *(const bf16x8*)(bz1p + (z + 2) * 8192 + kt * 32);
                z0[z + 2] = MFMA(a0s[kt], d0, z0[z + 2]);
                z1[z + 2] = MFMA(a0s[kt], d1, z1[z + 2]);
            }

        #pragma unroll
        for (int r = 0; r < 4; ++r) {
            const int r0 = quad * 4 + r;
            const float4 a = at4[n0 + r0];
            st0[r0][wave * 16 + l16] =
                m0[r] + a.x * z0[0][r] + a.y * z0[1][r] + a.z * z0[2][r] + a.w * z0[3][r];
            st0[r0][(wave + 4) * 16 + l16] =
                m1[r] + a.x * z1[0][r] + a.y * z1[1][r] + a.z * z1[2][r] + a.w * z1[3][r];
        }
    } else {
        // ---- t1 path ----
        const int ct = wave - 4;
        f32x4 mt[3] = {};
        #pragma unroll
        for (int kt = 0; kt < 4; ++kt) {
            #pragma unroll
            for (int rt = 0; rt < 3; ++rt) {
                const int row = rt * 16 + l16;
                const int off = row * 128 + kt * 32 + quad * 8;
                bf16x8 a = *(const bf16x8*)(sA2 + (off ^ ((row & 7) << 3)));
                mt[rt] = MFMA(a, PB[kt], mt[rt]);
            }
        }
        #pragma unroll
        for (int kt = 0; kt < 8; ++kt) {
            const bf16x8 b2 = (kt < 4) ? PB[4 + kt] : PC[kt - 4];
            #pragma unroll
            for (int rt = 0; rt < 3; ++rt) {
                const u32 xp = XQ[rt][kt];
                const float xa = bflo(xp), xb = bfhi(xp);
                bf16x8 af;
                af[0] = (short)f2bf(xa * atv[rt].x); af[1] = (short)f2bf(xa * atv[rt].y);
                af[2] = (short)f2bf(xa * atv[rt].z); af[3] = (short)f2bf(xa * atv[rt].w);
                af[4] = (short)f2bf(xb * atv[rt].x); af[5] = (short)f2bf(xb * atv[rt].y);
                af[6] = (short)f2bf(xb * atv[rt].z); af[7] = (short)f2bf(xb * atv[rt].w);
                mt[rt] = MFMA(af, b2, mt[rt]);
            }
        }

        #pragma unroll
        for (int r = 0; r < 4; ++r) {
            const int r0 = quad * 4 + r;
            st1[r0][ct * 16 + l16]      = mt[0][r];
            st1[16 + r0][ct * 16 + l16] = mt[1][r];
            st1[32 + r0][ct * 16 + l16] = mt[2][r];
        }
    }

    __syncthreads();

    #pragma unroll
    for (int i = 0; i < 8; ++i) {
        const int t = i * 2 + th;
        float o;
        if (c < 64) {
            o = xv[i] + silu(st0[t][c]);
        } else {
            int r = c - 64;
            int w = (r * 21846) >> 16;      // r/3
            int d = r - w * 3;
            o = xv[i] + silu(st0[t][64 + w]) * st1[t * 3 + d][w];
        }
        out[(size_t)(n0 + t) * 256 + c] = o;
    }
}

extern "C" void kernel_launch(void* const* d_in, const int* in_sizes, int n_in,
                              void* d_out, int out_size, void* d_ws, size_t ws_size,
                              hipStream_t stream) {
    const float* node_feats = (const float*)d_in[0];
    const float* node_attrs = (const float*)d_in[1];
    const float* edge_attrs = (const float*)d_in[2];
    const float* edge_emb   = (const float*)d_in[3];
    const float* W_lin1_0   = (const float*)d_in[4];
    const float* W_lin1_1   = (const float*)d_in[5];
    const float* W_mlp1     = (const float*)d_in[6];
    const float* W_mlp2     = (const float*)d_in[7];
    const float* W_lin2_0   = (const float*)d_in[8];
    const float* W_lin2_1   = (const float*)d_in[9];
    const float* W_sc0      = (const float*)d_in[10];
    const float* W_sc1      = (const float*)d_in[11];
    const int*   edge_index = (const int*)d_in[12];
    float* out = (float*)d_out;

    char* p = (char*)d_ws;
    float* hid = (float*)p;                 p += (size_t)E * 8 * 4;
    u16* hc    = (u16*)p;                   p += (size_t)N * 256 * 2;
    u16* A1    = (u16*)p;                   p += (size_t)N * 192 * 2;
    u16* A2g   = (u16*)p;                   p += (size_t)N * 3 * 128 * 2;
    u16* x1p   = (u16*)p;                   p += (size_t)N * 3 * 64 * 2;
    u16* Bt1m  = (u16*)p;                   p += 16384 * 2;
    u16* Bt1z  = (u16*)p;                   p += 32768 * 2;
    u16* Bt2   = (u16*)p;                   p += 24576 * 2;
    int* head  = (int*)p;                   p += N * 4;
    int2* nl   = (int2*)p;                  p += (size_t)E * 8;

    hipMemsetAsync(head, 0xFF, N * sizeof(int), stream);

    k_front<<<PREP_B + WCONV_B + HID_B + LIST_B, 256, 0, stream>>>(
        node_feats, edge_emb, edge_index,
        W_lin2_0, W_sc0, W_lin2_1, W_sc1, W_lin1_0, W_lin1_1, W_mlp1,
        A1, x1p, Bt1m, Bt1z, Bt2, hc, hid, head, nl);
    k_gather<<<N / 4, 256, 0, stream>>>(head, nl, edge_attrs, hid,
                                        (const u32*)hc, W_mlp2, A1, A2g);
    k_gemm_fused<<<1250, 512, 0, stream>>>(A1, A2g, x1p, Bt1m, Bt1z, Bt2,
                                           node_attrs, node_feats, out);
}